// Round 2
// baseline (732.332 us; speedup 1.0000x reference)
//
#include <hip/hip_runtime.h>

#define NEGV  (-1e30f)
#define LOG2E 1.4426950408889634f
#define LN2   0.6931471805599453f

namespace {
constexpr int B   = 64;
constexpr int T   = 2000;
constexpr int V   = 256;
constexpr int S   = 400;
constexpr int L   = 2 * S + 1;   // 801 extended states
constexpr int NT  = 256;         // 4 waves
constexpr int SPT = 4;           // states/thread -> covers 1024 >= 801
constexpr int CH  = 16;          // rows per staged chunk (CH*V = NT*16 floats)
constexpr int LP  = 1024 + 4;    // alpha buffer: 4-float NEG front pad
}

__device__ __forceinline__ float fexp2(float x) { return __builtin_amdgcn_exp2f(x); }
__device__ __forceinline__ float flog2(float x) { return __builtin_amdgcn_logf(x); }

// One block per batch item; 4 waves; alpha in registers (4 states/thread),
// LDS used for: staged logp rows (base-2 scaled), alpha mirror for the
// single halo value prev[s0-1] + final readout. One barrier per time step.
__global__ __launch_bounds__(NT)
void ctc_alpha_kernel(const float* __restrict__ logp,
                      const int* __restrict__ targets,
                      const int* __restrict__ input_len,
                      const int* __restrict__ target_len,
                      float* __restrict__ out)
{
  const int b   = blockIdx.x;
  const int tid = threadIdx.x;
  const float* lp = logp + (size_t)b * T * V;
  const int il = input_len[b];
  const int tl = target_len[b];
  const int Lb = 2 * tl + 1;
  const int s0 = tid * SPT;          // first owned state (even)

  __shared__ float rows[2][CH * V];  // 32 KB
  __shared__ float alph[2][LP];      // 8.2 KB

  // ---- t-invariant per-thread constants (odd states carry targets) ----
  const int* tg = targets + (size_t)b * S;
  int  e1 = 1, e3 = 1;
  bool sk1 = false, sk3 = false;
  {
    int k1 = (s0 + 1) >> 1;          // = s0/2
    int k3 = (s0 + 3) >> 1;          // = s0/2 + 1
    if (k1 < S) { e1 = tg[k1]; sk1 = (k1 == 0) || (e1 != tg[k1 - 1]); }
    if (k3 < S) { e3 = tg[k3]; sk3 = (e3 != tg[k3 - 1]); }   // k3 >= 1 always
  }
  const bool v0 = (s0 + 0 < Lb), v1 = (s0 + 1 < Lb),
             v2 = (s0 + 2 < Lb), v3 = (s0 + 3 < Lb);

  // ---- init alpha buffers (both, incl. pad) to NEG ----
  for (int i = tid; i < 2 * LP; i += NT) (&alph[0][0])[i] = NEGV;

  // ---- stage chunk 0 (rows 0..15), scaled to base-2 ----
  #pragma unroll
  for (int k = 0; k < 4; ++k) {
    float4 r = ((const float4*)lp)[tid + k * 256];
    r.x *= LOG2E; r.y *= LOG2E; r.z *= LOG2E; r.w *= LOG2E;
    ((float4*)&rows[0][0])[tid + k * 256] = r;
  }
  __syncthreads();

  // ---- t = 0 init ----
  float a0 = NEGV, a1 = NEGV, a2 = NEGV, a3 = NEGV;
  if (tid == 0) { a0 = rows[0][1]; a1 = rows[0][e1]; }
  *(float4*)&alph[0][s0 + 4] = make_float4(a0, a1, a2, a3);
  __syncthreads();

  // ---- main recursion: t in [1, il) ----
  int cur = 0;
  const int NCH = (il + CH - 1) / CH;
  for (int c = 0; c < NCH; ++c) {
    // prefetch next chunk into registers (global latency hidden behind CH steps)
    float4 pre[4];
    const bool ok = (c + 1 < NCH);
    if (ok) {
      const int base4 = (c + 1) * (CH * V / 4);
      #pragma unroll
      for (int k = 0; k < 4; ++k) pre[k] = ((const float4*)lp)[base4 + tid + k * 256];
    }
    const float* rowc = &rows[c & 1][0];
    const int iend = min(CH, il - c * CH);
    for (int i = (c == 0 ? 1 : 0); i < iend; ++i) {
      const float* ap = &alph[cur][0];
      float* an = &alph[cur ^ 1][0];
      const float* lrow = rowc + i * V;

      const float hl  = ap[s0 + 3];      // prev[s0-1] (pad-shifted) — only halo
      const float lpe = lrow[1];         // blank column (broadcast, conflict-free)
      const float lp1 = lrow[e1];
      const float lp3 = lrow[e3];

      // j=2 (even/blank): lse2(a2, a1)
      float n2; {
        float m = fmaxf(a2, a1);
        n2 = m + flog2(fexp2(a2 - m) + fexp2(a1 - m)) + lpe;
      }
      // j=3 (odd): lse3(a3, a2, sk3 ? a1)
      float n3; {
        float z = sk3 ? a1 : NEGV;
        float m = fmaxf(fmaxf(a3, a2), z);
        n3 = m + flog2(fexp2(a3 - m) + fexp2(a2 - m) + fexp2(z - m)) + lp3;
      }
      // j=0 (even/blank): lse2(a0, hl)
      float n0; {
        float m = fmaxf(a0, hl);
        n0 = m + flog2(fexp2(a0 - m) + fexp2(hl - m)) + lpe;
      }
      // j=1 (odd): lse3(a1, a0, sk1 ? hl)
      float n1; {
        float z = sk1 ? hl : NEGV;
        float m = fmaxf(fmaxf(a1, a0), z);
        n1 = m + flog2(fexp2(a1 - m) + fexp2(a0 - m) + fexp2(z - m)) + lp1;
      }

      a0 = v0 ? n0 : NEGV;
      a1 = v1 ? n1 : NEGV;
      a2 = v2 ? n2 : NEGV;
      a3 = v3 ? n3 : NEGV;
      *(float4*)&an[s0 + 4] = make_float4(a0, a1, a2, a3);
      __syncthreads();
      cur ^= 1;
    }
    // commit prefetched chunk (scaled) into the other row buffer
    if (ok) {
      #pragma unroll
      for (int k = 0; k < 4; ++k) {
        float4 r = pre[k];
        r.x *= LOG2E; r.y *= LOG2E; r.z *= LOG2E; r.w *= LOG2E;
        ((float4*)&rows[(c & 1) ^ 1][0])[tid + k * 256] = r;
      }
    }
    __syncthreads();
  }

  // ---- readout + fused mean via one atomic per block ----
  if (tid == 0) {
    const float* ap = &alph[cur][0];
    const float ae  = ap[2 * tl + 4];
    const float ae1 = ap[2 * tl + 3];
    const float m   = fmaxf(ae, ae1);
    const float ll  = (m + flog2(fexp2(ae - m) + fexp2(ae1 - m))) * LN2;
    float loss = -ll;
    if (!(loss < 1e29f)) loss = 0.0f;
    atomicAdd(out, loss / ((float)tl * (float)B));
  }
}

__global__ void ctc_zero_kernel(float* __restrict__ out) { out[0] = 0.0f; }

extern "C" void kernel_launch(void* const* d_in, const int* in_sizes, int n_in,
                              void* d_out, int out_size, void* d_ws, size_t ws_size,
                              hipStream_t stream) {
  const float* logp    = (const float*)d_in[0];
  const int*   targets = (const int*)d_in[1];
  const int*   il      = (const int*)d_in[2];
  const int*   tl      = (const int*)d_in[3];
  float* out = (float*)d_out;

  ctc_zero_kernel<<<1, 1, 0, stream>>>(out);
  ctc_alpha_kernel<<<B, NT, 0, stream>>>(logp, targets, il, tl, out);
}